// Round 1
// baseline (849.879 us; speedup 1.0000x reference)
//
#include <hip/hip_runtime.h>

#define DEVI __device__ __forceinline__

typedef __attribute__((ext_vector_type(8))) short short8;
typedef __attribute__((ext_vector_type(4))) float f32x4;
typedef unsigned short u16;
typedef unsigned int u32;

DEVI float b2f(u16 u) { u32 x = ((u32)u) << 16; return __builtin_bit_cast(float, x); }
DEVI u16 f2b(float f) {
    u32 u = __builtin_bit_cast(u32, f);
    u32 r = u + 0x7FFFu + ((u >> 16) & 1u);   // RNE
    return (u16)(r >> 16);
}
DEVI float elu(float v) { return v > 0.f ? v : expm1f(v); }

DEVI void gl16(const void* g, void* l) {
    __builtin_amdgcn_global_load_lds(
        (const __attribute__((address_space(1))) u32*)g,
        (__attribute__((address_space(3))) u32*)l, 16, 0, 0);
}

// ---------------- elementwise fp32 -> bf16 ----------------
__global__ void k_convert(const float* __restrict__ in, u16* __restrict__ out, int n) {
    int i = blockIdx.x * blockDim.x + threadIdx.x;
    int stride = gridDim.x * blockDim.x;
    for (int j = i; j * 8 < n; j += stride) {
        int base = j * 8;
        if (base + 8 <= n) {
            float4 a = *(const float4*)(in + base);
            float4 b = *(const float4*)(in + base + 4);
            short8 o;
            o[0] = (short)f2b(a.x); o[1] = (short)f2b(a.y);
            o[2] = (short)f2b(a.z); o[3] = (short)f2b(a.w);
            o[4] = (short)f2b(b.x); o[5] = (short)f2b(b.y);
            o[6] = (short)f2b(b.z); o[7] = (short)f2b(b.w);
            *(short8*)(out + base) = o;
        } else {
            for (int t = base; t < n; ++t) out[t] = f2b(in[t]);
        }
    }
}

// ---------------- build WcT (512 x 128) from w_m1a (512 x 256) ----------------
// Wc[k][j] = w_m1a[k][j] + w_m1a[k+128][j]          (j < 256, dst part)
// Wc[k][256+j] = w_m1a[k+256][j] + w_m1a[k+384][j]  (src part)
// stored transposed: WcT[j][k]
__global__ void k_wct(const float* __restrict__ w, u16* __restrict__ wct) {
    int t = blockIdx.x * 256 + threadIdx.x;
    if (t >= 512 * 128) return;
    int k = t & 127, j = t >> 7;
    float v;
    if (j < 256) v = w[k * 256 + j] + w[(k + 128) * 256 + j];
    else { int jj = j - 256; v = w[(k + 256) * 256 + jj] + w[(k + 384) * 256 + jj]; }
    wct[j * 128 + k] = f2b(v);
}

// ---------------- transpose-convert: W (K x N fp32) -> WT (Nalloc x K bf16) ----------------
__global__ void k_tc(const float* __restrict__ w, u16* __restrict__ wt,
                     int K, int N, int Nalloc) {
    __shared__ float tile[32][33];
    int tx = threadIdx.x, ty = threadIdx.y;
    int k0 = blockIdx.y * 32, n0 = blockIdx.x * 32;
#pragma unroll
    for (int yy = 0; yy < 4; ++yy) {
        int k = k0 + ty + yy * 8, n = n0 + tx;
        tile[ty + yy * 8][tx] = (k < K && n < N) ? w[(size_t)k * N + n] : 0.f;
    }
    __syncthreads();
#pragma unroll
    for (int yy = 0; yy < 4; ++yy) {
        int n = n0 + ty + yy * 8, k = k0 + tx;
        if (n < Nalloc && k < K) wt[(size_t)n * K + k] = f2b(tile[tx][ty + yy * 8]);
    }
}

// ---------------- generic bf16 GEMM: C = epi(A @ BT^T + bias) ----------------
// A: M x K (row-major, lda, rows padded to 128-mult), BT: N x K (row-major, ldbt,
// rows padded to 128-mult). 128x128 tile, BK=64, 4 waves, mfma 16x16x32 bf16.
// EPI: 0 = none->bf16, 1 = ELU->bf16, 2 = ReLU->bf16, 3 = sigmoid->fp32
template <int EPI>
__global__ __launch_bounds__(256, 2)
void k_gemm(const u16* __restrict__ A, const u16* __restrict__ BT,
            const float* __restrict__ bias, void* __restrict__ Cv,
            int M, int N, int K, int lda, int ldbt, int ldc) {
    __shared__ short lsA[128 * 64];
    __shared__ short lsB[128 * 64];
    const int tid = threadIdx.x, wave = tid >> 6, lane = tid & 63;
    const int m0 = blockIdx.y * 128, n0 = blockIdx.x * 128;
    const int wm = wave >> 1, wn = wave & 1;
    const int rowA = lane >> 3, colA = (lane & 7) * 8;

    f32x4 acc[4][4] = {};

    const int kch = K >> 6;
    for (int kc = 0; kc < kch; ++kc) {
#pragma unroll
        for (int i = 0; i < 4; ++i) {
            int slot = wave * 4 + i;                     // 0..15, 8 rows each
            const u16* ga = A + (size_t)(m0 + slot * 8 + rowA) * lda + kc * 64 + colA;
            gl16(ga, &lsA[slot * 512]);
            const u16* gb = BT + (size_t)(n0 + slot * 8 + rowA) * ldbt + kc * 64 + colA;
            gl16(gb, &lsB[slot * 512]);
        }
        __syncthreads();
#pragma unroll
        for (int ks = 0; ks < 2; ++ks) {
            short8 a[4], b[4];
#pragma unroll
            for (int m = 0; m < 4; ++m)
                a[m] = *(const short8*)&lsA[(wm * 64 + m * 16 + (lane & 15)) * 64 + ks * 32 + (lane >> 4) * 8];
#pragma unroll
            for (int n = 0; n < 4; ++n)
                b[n] = *(const short8*)&lsB[(wn * 64 + n * 16 + (lane & 15)) * 64 + ks * 32 + (lane >> 4) * 8];
#pragma unroll
            for (int m = 0; m < 4; ++m)
#pragma unroll
                for (int n = 0; n < 4; ++n)
                    acc[m][n] = __builtin_amdgcn_mfma_f32_16x16x32_bf16(a[m], b[n], acc[m][n], 0, 0, 0);
        }
        __syncthreads();
    }

#pragma unroll
    for (int m = 0; m < 4; ++m) {
#pragma unroll
        for (int n = 0; n < 4; ++n) {
            int colg = n0 + wn * 64 + n * 16 + (lane & 15);
#pragma unroll
            for (int j = 0; j < 4; ++j) {
                int rowg = m0 + wm * 64 + m * 16 + (lane >> 4) * 4 + j;
                if (rowg < M && colg < N) {
                    float v = acc[m][n][j];
                    if (bias) v += bias[colg];
                    if (EPI == 1) v = elu(v);
                    if (EPI == 2) v = v > 0.f ? v : 0.f;
                    if (EPI == 3) {
                        v = 1.f / (1.f + __expf(-v));
                        ((float*)Cv)[(size_t)rowg * ldc + colg] = v;
                    } else {
                        ((u16*)Cv)[(size_t)rowg * ldc + colg] = f2b(v);
                    }
                }
            }
        }
    }
}

// ---------------- edge kernel: layer1-ELU (from node projections) + GEMM w_m1b + ELU + atomic segsum ----------------
// P: N x 512 bf16 ([pd | ps]); per block 128 edges. A-tile computed into LDS,
// B = w_m1bT (256 x 256) staged per 128-col half. agg += ELU(t @ w_m1b + b2).
__global__ __launch_bounds__(256, 1)
void k_edge(const u16* __restrict__ P, const int* __restrict__ ei,
            const float* __restrict__ b1, const u16* __restrict__ W2T,
            const float* __restrict__ b2, float* __restrict__ agg, int E) {
    __shared__ short lsA[128 * 256];   // 64 KB: 128 edges x K=256
    __shared__ short lsB[128 * 256];   // 64 KB: 128 cols x K=256 (one N-half)
    __shared__ int dstl[128];
    __shared__ int srcl[128];
    const int tid = threadIdx.x, wave = tid >> 6, lane = tid & 63;
    const int eb = blockIdx.x * 128;

    if (tid < 128) srcl[tid] = ei[eb + tid];
    else dstl[tid - 128] = ei[E + eb + (tid - 128)];
    __syncthreads();

    // compute A tile: t = ELU(pd[dst] + ps[src] + b1), bf16, lane-contiguous writes
    for (int it = 0; it < 16; ++it) {
        int chunk = tid + it * 256;            // 0..4095 (16B chunks of the 64KB tile)
        int r = chunk >> 5, c = (chunk & 31) * 8;
        int d = dstl[r], s = srcl[r];
        short8 pd = *(const short8*)(P + (size_t)d * 512 + c);
        short8 ps = *(const short8*)(P + (size_t)s * 512 + 256 + c);
        short8 o;
#pragma unroll
        for (int j = 0; j < 8; ++j) {
            float v = b2f((u16)pd[j]) + b2f((u16)ps[j]) + b1[c + j];
            o[j] = (short)f2b(elu(v));
        }
        *(short8*)&lsA[chunk * 8] = o;
    }

    const int wm = wave >> 1, wn = wave & 1;
    for (int nh = 0; nh < 2; ++nh) {
#pragma unroll
        for (int i = 0; i < 16; ++i) {
            int slot = wave * 16 + i;          // 64 slots x 1KB = 64KB, 2 rows/slot
            const u16* gb = W2T + (size_t)(nh * 128 + slot * 2 + (lane >> 5)) * 256 + (lane & 31) * 8;
            gl16(gb, &lsB[slot * 512]);
        }
        __syncthreads();                       // drains vmcnt (B) + lgkm (A writes)

        f32x4 acc[4][4] = {};
#pragma unroll
        for (int ks = 0; ks < 8; ++ks) {
            short8 a[4], b[4];
#pragma unroll
            for (int m = 0; m < 4; ++m)
                a[m] = *(const short8*)&lsA[(wm * 64 + m * 16 + (lane & 15)) * 256 + ks * 32 + (lane >> 4) * 8];
#pragma unroll
            for (int n = 0; n < 4; ++n)
                b[n] = *(const short8*)&lsB[(wn * 64 + n * 16 + (lane & 15)) * 256 + ks * 32 + (lane >> 4) * 8];
#pragma unroll
            for (int m = 0; m < 4; ++m)
#pragma unroll
                for (int n = 0; n < 4; ++n)
                    acc[m][n] = __builtin_amdgcn_mfma_f32_16x16x32_bf16(a[m], b[n], acc[m][n], 0, 0, 0);
        }
#pragma unroll
        for (int m = 0; m < 4; ++m) {
#pragma unroll
            for (int n = 0; n < 4; ++n) {
                int col = wn * 64 + n * 16 + (lane & 15);
#pragma unroll
                for (int j = 0; j < 4; ++j) {
                    int row = wm * 64 + m * 16 + (lane >> 4) * 4 + j;
                    float v = elu(acc[m][n][j] + b2[nh * 128 + col]);
                    atomicAdd(&agg[(size_t)dstl[row] * 256 + nh * 128 + col], v);
                }
            }
        }
        __syncthreads();                       // before restaging lsB
    }
}

extern "C" void kernel_launch(void* const* d_in, const int* in_sizes, int n_in,
                              void* d_out, int out_size, void* d_ws, size_t ws_size,
                              hipStream_t stream) {
    const float* api    = (const float*)d_in[0];
    const int*   ei     = (const int*)d_in[2];
    const float* w_m1a  = (const float*)d_in[7];
    const float* b_m1a  = (const float*)d_in[8];
    const float* w_m1b  = (const float*)d_in[9];
    const float* b_m1b  = (const float*)d_in[10];
    const float* w_m2a  = (const float*)d_in[11];
    const float* b_m2a  = (const float*)d_in[12];
    const float* w_m2b  = (const float*)d_in[13];
    const float* b_m2b  = (const float*)d_in[14];
    const float* w_ma   = (const float*)d_in[15];
    const float* b_ma   = (const float*)d_in[16];
    const float* w_mb   = (const float*)d_in[17];
    const float* b_mb   = (const float*)d_in[18];
    const float* w_inc1 = (const float*)d_in[19];
    const float* b_inc1 = (const float*)d_in[20];
    const float* w_inc2 = (const float*)d_in[21];
    const float* b_inc2 = (const float*)d_in[22];

    const int N = 10000, C = 128, E = 320000, Mp = 10112;   // Mp = 79*128

    char* w = (char*)d_ws;
    size_t off = 0;
    auto alloc = [&](size_t bytes) { void* p = w + off; off += (bytes + 255) & ~(size_t)255; return p; };
    u16* e16   = (u16*)alloc((size_t)Mp * 128 * 2);
    u16* WcT   = (u16*)alloc(512 * 128 * 2);
    u16* P     = (u16*)alloc((size_t)Mp * 512 * 2);
    u16* w1bT  = (u16*)alloc(256 * 256 * 2);
    u16* w2aT  = (u16*)alloc(256 * 256 * 2);
    u16* w2bT  = (u16*)alloc(256 * 256 * 2);
    u16* waT   = (u16*)alloc(256 * 256 * 2);
    u16* wbT   = (u16*)alloc(256 * 256 * 2);
    u16* i1T   = (u16*)alloc(384 * 128 * 2);
    u16* i2T   = (u16*)alloc((size_t)Mp * 384 * 2);
    float* agg = (float*)alloc((size_t)N * 256 * 4);
    u16* agg16 = (u16*)alloc((size_t)Mp * 256 * 2);
    u16* hbA   = (u16*)alloc((size_t)Mp * 256 * 2);
    u16* hbB   = (u16*)alloc((size_t)Mp * 256 * 2);
    u16* H1    = (u16*)alloc((size_t)Mp * 384 * 2);
    (void)ws_size; (void)in_sizes; (void)n_in; (void)out_size;

    dim3 tb(32, 8);
    k_convert<<<640, 256, 0, stream>>>(api, e16, N * C);
    k_wct<<<256, 256, 0, stream>>>(w_m1a, WcT);
    k_tc<<<dim3(8, 8),  tb, 0, stream>>>(w_m1b,  w1bT, 256, 256, 256);
    k_tc<<<dim3(8, 8),  tb, 0, stream>>>(w_m2a,  w2aT, 256, 256, 256);
    k_tc<<<dim3(8, 8),  tb, 0, stream>>>(w_m2b,  w2bT, 256, 256, 256);
    k_tc<<<dim3(8, 8),  tb, 0, stream>>>(w_ma,   waT,  256, 256, 256);
    k_tc<<<dim3(8, 8),  tb, 0, stream>>>(w_mb,   wbT,  256, 256, 256);
    k_tc<<<dim3(12, 4), tb, 0, stream>>>(w_inc1, i1T,  128, 384, 384);
    k_tc<<<dim3(316, 12), tb, 0, stream>>>(w_inc2, i2T, 384, 10000, Mp);
    hipMemsetAsync(agg, 0, (size_t)N * 256 * 4, stream);

    // P = e @ Wc  (node projections [pd | ps])
    k_gemm<0><<<dim3(4, 79), 256, 0, stream>>>(e16, WcT, nullptr, P, N, 512, 128, 128, 128, 512);
    // edge layer + segment-sum
    k_edge<<<2500, 256, 0, stream>>>(P, ei, b_m1a, w1bT, b_m1b, agg, E);
    k_convert<<<640, 256, 0, stream>>>(agg, agg16, N * 256);
    // node MLPs
    k_gemm<1><<<dim3(2, 79), 256, 0, stream>>>(agg16, w2aT, b_m2a, hbA, N, 256, 256, 256, 256, 256);
    k_gemm<1><<<dim3(2, 79), 256, 0, stream>>>(hbA,   w2bT, b_m2b, hbB, N, 256, 256, 256, 256, 256);
    k_gemm<1><<<dim3(2, 79), 256, 0, stream>>>(hbB,   waT,  b_ma,  hbA, N, 256, 256, 256, 256, 256);
    k_gemm<1><<<dim3(2, 79), 256, 0, stream>>>(hbA,   wbT,  b_mb,  hbB, N, 256, 256, 256, 256, 256);
    // h[:, -128:] @ w_inc1, ReLU
    k_gemm<2><<<dim3(3, 79), 256, 0, stream>>>(hbB + 128, i1T, b_inc1, H1, N, 384, 128, 256, 128, 384);
    // final: sigmoid(H1 @ w_inc2 + b_inc2) -> d_out fp32
    k_gemm<3><<<dim3(79, 79), 256, 0, stream>>>(H1, i2T, b_inc2, d_out, N, 10000, 384, 384, 384, 10000);
}

// Round 2
// 643.639 us; speedup vs baseline: 1.3204x; 1.3204x over previous
//
#include <hip/hip_runtime.h>

#define DEVI __device__ __forceinline__

typedef __attribute__((ext_vector_type(8))) short short8;
typedef __attribute__((ext_vector_type(4))) float f32x4;
typedef unsigned short u16;
typedef unsigned int u32;

DEVI float b2f(u16 u) { u32 x = ((u32)u) << 16; return __builtin_bit_cast(float, x); }
DEVI u16 f2b(float f) {
    u32 u = __builtin_bit_cast(u32, f);
    u32 r = u + 0x7FFFu + ((u >> 16) & 1u);   // RNE
    return (u16)(r >> 16);
}
// fast ELU: exp(v)-1 instead of expm1f; abs err ~1e-7, fine for bf16 pipeline
DEVI float eluf(float v) { return v > 0.f ? v : __expf(v) - 1.f; }

DEVI void gl16(const void* g, void* l) {
    __builtin_amdgcn_global_load_lds(
        (const __attribute__((address_space(1))) u32*)g,
        (__attribute__((address_space(3))) u32*)l, 16, 0, 0);
}

// ---------------- elementwise fp32 -> bf16 ----------------
__global__ void k_convert(const float* __restrict__ in, u16* __restrict__ out, int n) {
    int i = blockIdx.x * blockDim.x + threadIdx.x;
    int stride = gridDim.x * blockDim.x;
    for (int j = i; j * 8 < n; j += stride) {
        int base = j * 8;
        if (base + 8 <= n) {
            float4 a = *(const float4*)(in + base);
            float4 b = *(const float4*)(in + base + 4);
            short8 o;
            o[0] = (short)f2b(a.x); o[1] = (short)f2b(a.y);
            o[2] = (short)f2b(a.z); o[3] = (short)f2b(a.w);
            o[4] = (short)f2b(b.x); o[5] = (short)f2b(b.y);
            o[6] = (short)f2b(b.z); o[7] = (short)f2b(b.w);
            *(short8*)(out + base) = o;
        } else {
            for (int t = base; t < n; ++t) out[t] = f2b(in[t]);
        }
    }
}

// ---------------- build WcT (512 x 128) from w_m1a (512 x 256) ----------------
__global__ void k_wct(const float* __restrict__ w, u16* __restrict__ wct) {
    int t = blockIdx.x * 256 + threadIdx.x;
    if (t >= 512 * 128) return;
    int k = t & 127, j = t >> 7;
    float v;
    if (j < 256) v = w[k * 256 + j] + w[(k + 128) * 256 + j];
    else { int jj = j - 256; v = w[(k + 256) * 256 + jj] + w[(k + 384) * 256 + jj]; }
    wct[j * 128 + k] = f2b(v);
}

// ---------------- transpose-convert: W (K x N fp32) -> WT (Nalloc x K bf16) ----------------
__global__ void k_tc(const float* __restrict__ w, u16* __restrict__ wt,
                     int K, int N, int Nalloc) {
    __shared__ float tile[32][33];
    int tx = threadIdx.x, ty = threadIdx.y;
    int k0 = blockIdx.y * 32, n0 = blockIdx.x * 32;
#pragma unroll
    for (int yy = 0; yy < 4; ++yy) {
        int k = k0 + ty + yy * 8, n = n0 + tx;
        tile[ty + yy * 8][tx] = (k < K && n < N) ? w[(size_t)k * N + n] : 0.f;
    }
    __syncthreads();
#pragma unroll
    for (int yy = 0; yy < 4; ++yy) {
        int n = n0 + ty + yy * 8, k = k0 + tx;
        if (n < Nalloc && k < K) wt[(size_t)n * K + k] = f2b(tile[tx][ty + yy * 8]);
    }
}

// ---------------- generic bf16 GEMM: C = epi(A @ BT^T + bias) ----------------
// EPI: 0 = none->bf16, 1 = ELU->bf16, 2 = ReLU->bf16, 3 = sigmoid->fp32
template <int EPI>
__global__ __launch_bounds__(256, 2)
void k_gemm(const u16* __restrict__ A, const u16* __restrict__ BT,
            const float* __restrict__ bias, void* __restrict__ Cv,
            int M, int N, int K, int lda, int ldbt, int ldc) {
    __shared__ short lsA[128 * 64];
    __shared__ short lsB[128 * 64];
    const int tid = threadIdx.x, wave = tid >> 6, lane = tid & 63;
    const int m0 = blockIdx.y * 128, n0 = blockIdx.x * 128;
    const int wm = wave >> 1, wn = wave & 1;
    const int rowA = lane >> 3, colA = (lane & 7) * 8;

    f32x4 acc[4][4] = {};

    const int kch = K >> 6;
    for (int kc = 0; kc < kch; ++kc) {
#pragma unroll
        for (int i = 0; i < 4; ++i) {
            int slot = wave * 4 + i;
            const u16* ga = A + (size_t)(m0 + slot * 8 + rowA) * lda + kc * 64 + colA;
            gl16(ga, &lsA[slot * 512]);
            const u16* gb = BT + (size_t)(n0 + slot * 8 + rowA) * ldbt + kc * 64 + colA;
            gl16(gb, &lsB[slot * 512]);
        }
        __syncthreads();
#pragma unroll
        for (int ks = 0; ks < 2; ++ks) {
            short8 a[4], b[4];
#pragma unroll
            for (int m = 0; m < 4; ++m)
                a[m] = *(const short8*)&lsA[(wm * 64 + m * 16 + (lane & 15)) * 64 + ks * 32 + (lane >> 4) * 8];
#pragma unroll
            for (int n = 0; n < 4; ++n)
                b[n] = *(const short8*)&lsB[(wn * 64 + n * 16 + (lane & 15)) * 64 + ks * 32 + (lane >> 4) * 8];
#pragma unroll
            for (int m = 0; m < 4; ++m)
#pragma unroll
                for (int n = 0; n < 4; ++n)
                    acc[m][n] = __builtin_amdgcn_mfma_f32_16x16x32_bf16(a[m], b[n], acc[m][n], 0, 0, 0);
        }
        __syncthreads();
    }

#pragma unroll
    for (int m = 0; m < 4; ++m) {
#pragma unroll
        for (int n = 0; n < 4; ++n) {
            int colg = n0 + wn * 64 + n * 16 + (lane & 15);
#pragma unroll
            for (int j = 0; j < 4; ++j) {
                int rowg = m0 + wm * 64 + m * 16 + (lane >> 4) * 4 + j;
                if (rowg < M && colg < N) {
                    float v = acc[m][n][j];
                    if (bias) v += bias[colg];
                    if (EPI == 1) v = eluf(v);
                    if (EPI == 2) v = v > 0.f ? v : 0.f;
                    if (EPI == 3) {
                        v = 1.f / (1.f + __expf(-v));
                        ((float*)Cv)[(size_t)rowg * ldc + colg] = v;
                    } else {
                        ((u16*)Cv)[(size_t)rowg * ldc + colg] = f2b(v);
                    }
                }
            }
        }
    }
}

// ---------------- edge kernel v2 ----------------
// 128 edges/block, 4 waves, 2 blocks/CU (73KB LDS). A tile 128x256 (64KB,
// XOR-swizzled, computed once). B staged as 64x64 (8KB) chunks via gl16 with
// pre-swizzled source. agg += ELU(ELU(pd[dst]+ps[src]+b1) @ w_m1b + b2).
__global__ __launch_bounds__(256, 2)
void k_edge(const u16* __restrict__ P, const int* __restrict__ ei,
            const float* __restrict__ b1, const u16* __restrict__ W2T,
            const float* __restrict__ b2, float* __restrict__ agg, int E) {
    __shared__ short lsA[128 * 256];   // 64KB
    __shared__ short lsB[64 * 64];     // 8KB
    __shared__ int dstl[128];
    __shared__ int srcl[128];
    const int tid = threadIdx.x, wave = tid >> 6, lane = tid & 63;
    const int eb = blockIdx.x * 128;
    const int g = lane >> 4, l15 = lane & 15;

    if (tid < 128) srcl[tid] = ei[eb + tid];
    else dstl[tid - 128] = ei[E + eb + (tid - 128)];
    __syncthreads();

    // A tile: t = ELU(pd[dst] + ps[src] + b1), swizzle 16B-chunk idx: cc ^= (row&7)
#pragma unroll 4
    for (int it = 0; it < 16; ++it) {
        int chunk = it * 256 + tid;            // 0..4095
        int r = chunk >> 5, cc = chunk & 31;
        int d = dstl[r], s = srcl[r];
        short8 pd = *(const short8*)(P + (size_t)d * 512 + cc * 8);
        short8 ps = *(const short8*)(P + (size_t)s * 512 + 256 + cc * 8);
        float bvals[8];
        *(float4*)&bvals[0] = *(const float4*)(b1 + cc * 8);
        *(float4*)&bvals[4] = *(const float4*)(b1 + cc * 8 + 4);
        short8 o;
#pragma unroll
        for (int jj = 0; jj < 8; ++jj) {
            float v = b2f((u16)pd[jj]) + b2f((u16)ps[jj]) + bvals[jj];
            o[jj] = (short)f2b(eluf(v));
        }
        int ccs = (cc & 24) | ((cc ^ r) & 7);
        *(short8*)&lsA[(r * 32 + ccs) * 8] = o;
    }
    // (A-write lgkm drained by the first __syncthreads below)

    for (int nq = 0; nq < 4; ++nq) {
        f32x4 acc[2][4] = {};
        for (int kc = 0; kc < 4; ++kc) {
            // stage B chunk: 64 outcols x 64 k, linear dest + inverse-swizzled source
#pragma unroll
            for (int i = 0; i < 2; ++i) {
                int s = wave * 2 + i;                  // 8 slots x 1KB
                int br = s * 8 + (lane >> 3);
                const u16* gb = W2T + (size_t)(nq * 64 + br) * 256 + kc * 64
                              + (((lane & 7) ^ (br & 7)) * 8);
                gl16(gb, &lsB[s * 512]);
            }
            __syncthreads();
#pragma unroll
            for (int ks = 0; ks < 2; ++ks) {
                short8 a[2], b[4];
#pragma unroll
                for (int m = 0; m < 2; ++m) {
                    int ar = wave * 32 + m * 16 + l15;
                    a[m] = *(const short8*)&lsA[ar * 256 + (kc * 8 + ((ks * 4 + g) ^ (ar & 7))) * 8];
                }
#pragma unroll
                for (int n = 0; n < 4; ++n) {
                    int br = n * 16 + l15;
                    b[n] = *(const short8*)&lsB[br * 64 + (((ks * 4 + g) ^ (br & 7)) * 8)];
                }
#pragma unroll
                for (int m = 0; m < 2; ++m)
#pragma unroll
                    for (int n = 0; n < 4; ++n)
                        acc[m][n] = __builtin_amdgcn_mfma_f32_16x16x32_bf16(a[m], b[n], acc[m][n], 0, 0, 0);
            }
            __syncthreads();
        }
        // epilogue for this 64-col quarter
        float b2v[4];
#pragma unroll
        for (int n = 0; n < 4; ++n) b2v[n] = b2[nq * 64 + n * 16 + l15];
#pragma unroll
        for (int m = 0; m < 2; ++m) {
#pragma unroll
            for (int j = 0; j < 4; ++j) {
                int row = wave * 32 + m * 16 + g * 4 + j;
                float* rp = agg + (size_t)dstl[row] * 256 + nq * 64 + l15;
#pragma unroll
                for (int n = 0; n < 4; ++n)
                    atomicAdd(rp + n * 16, eluf(acc[m][n][j] + b2v[n]));
            }
        }
    }
}

extern "C" void kernel_launch(void* const* d_in, const int* in_sizes, int n_in,
                              void* d_out, int out_size, void* d_ws, size_t ws_size,
                              hipStream_t stream) {
    const float* api    = (const float*)d_in[0];
    const int*   ei     = (const int*)d_in[2];
    const float* w_m1a  = (const float*)d_in[7];
    const float* b_m1a  = (const float*)d_in[8];
    const float* w_m1b  = (const float*)d_in[9];
    const float* b_m1b  = (const float*)d_in[10];
    const float* w_m2a  = (const float*)d_in[11];
    const float* b_m2a  = (const float*)d_in[12];
    const float* w_m2b  = (const float*)d_in[13];
    const float* b_m2b  = (const float*)d_in[14];
    const float* w_ma   = (const float*)d_in[15];
    const float* b_ma   = (const float*)d_in[16];
    const float* w_mb   = (const float*)d_in[17];
    const float* b_mb   = (const float*)d_in[18];
    const float* w_inc1 = (const float*)d_in[19];
    const float* b_inc1 = (const float*)d_in[20];
    const float* w_inc2 = (const float*)d_in[21];
    const float* b_inc2 = (const float*)d_in[22];

    const int N = 10000, C = 128, E = 320000, Mp = 10112;   // Mp = 79*128

    char* w = (char*)d_ws;
    size_t off = 0;
    auto alloc = [&](size_t bytes) { void* p = w + off; off += (bytes + 255) & ~(size_t)255; return p; };
    u16* e16   = (u16*)alloc((size_t)Mp * 128 * 2);
    u16* WcT   = (u16*)alloc(512 * 128 * 2);
    u16* P     = (u16*)alloc((size_t)Mp * 512 * 2);
    u16* w1bT  = (u16*)alloc(256 * 256 * 2);
    u16* w2aT  = (u16*)alloc(256 * 256 * 2);
    u16* w2bT  = (u16*)alloc(256 * 256 * 2);
    u16* waT   = (u16*)alloc(256 * 256 * 2);
    u16* wbT   = (u16*)alloc(256 * 256 * 2);
    u16* i1T   = (u16*)alloc(384 * 128 * 2);
    u16* i2T   = (u16*)alloc((size_t)Mp * 384 * 2);
    float* agg = (float*)alloc((size_t)N * 256 * 4);
    u16* agg16 = (u16*)alloc((size_t)Mp * 256 * 2);
    u16* hbA   = (u16*)alloc((size_t)Mp * 256 * 2);
    u16* hbB   = (u16*)alloc((size_t)Mp * 256 * 2);
    u16* H1    = (u16*)alloc((size_t)Mp * 384 * 2);
    (void)ws_size; (void)in_sizes; (void)n_in; (void)out_size;

    dim3 tb(32, 8);
    k_convert<<<640, 256, 0, stream>>>(api, e16, N * C);
    k_wct<<<256, 256, 0, stream>>>(w_m1a, WcT);
    k_tc<<<dim3(8, 8),  tb, 0, stream>>>(w_m1b,  w1bT, 256, 256, 256);
    k_tc<<<dim3(8, 8),  tb, 0, stream>>>(w_m2a,  w2aT, 256, 256, 256);
    k_tc<<<dim3(8, 8),  tb, 0, stream>>>(w_m2b,  w2bT, 256, 256, 256);
    k_tc<<<dim3(8, 8),  tb, 0, stream>>>(w_ma,   waT,  256, 256, 256);
    k_tc<<<dim3(8, 8),  tb, 0, stream>>>(w_mb,   wbT,  256, 256, 256);
    k_tc<<<dim3(12, 4), tb, 0, stream>>>(w_inc1, i1T,  128, 384, 384);
    k_tc<<<dim3(316, 12), tb, 0, stream>>>(w_inc2, i2T, 384, 10000, Mp);
    hipMemsetAsync(agg, 0, (size_t)N * 256 * 4, stream);

    // P = e @ Wc  (node projections [pd | ps])
    k_gemm<0><<<dim3(4, 79), 256, 0, stream>>>(e16, WcT, nullptr, P, N, 512, 128, 128, 128, 512);
    // edge layer + segment-sum
    k_edge<<<2500, 256, 0, stream>>>(P, ei, b_m1a, w1bT, b_m1b, agg, E);
    k_convert<<<640, 256, 0, stream>>>(agg, agg16, N * 256);
    // node MLPs
    k_gemm<1><<<dim3(2, 79), 256, 0, stream>>>(agg16, w2aT, b_m2a, hbA, N, 256, 256, 256, 256, 256);
    k_gemm<1><<<dim3(2, 79), 256, 0, stream>>>(hbA,   w2bT, b_m2b, hbB, N, 256, 256, 256, 256, 256);
    k_gemm<1><<<dim3(2, 79), 256, 0, stream>>>(hbB,   waT,  b_ma,  hbA, N, 256, 256, 256, 256, 256);
    k_gemm<1><<<dim3(2, 79), 256, 0, stream>>>(hbA,   wbT,  b_mb,  hbB, N, 256, 256, 256, 256, 256);
    // h[:, -128:] @ w_inc1, ReLU
    k_gemm<2><<<dim3(3, 79), 256, 0, stream>>>(hbB + 128, i1T, b_inc1, H1, N, 384, 128, 256, 128, 384);
    // final: sigmoid(H1 @ w_inc2 + b_inc2) -> d_out fp32
    k_gemm<3><<<dim3(79, 79), 256, 0, stream>>>(H1, i2T, b_inc2, d_out, N, 10000, 384, 384, 384, 10000);
}

// Round 3
// 602.729 us; speedup vs baseline: 1.4101x; 1.0679x over previous
//
#include <hip/hip_runtime.h>

#define DEVI __device__ __forceinline__

typedef __attribute__((ext_vector_type(8))) short short8;
typedef __attribute__((ext_vector_type(4))) float f32x4;
typedef unsigned short u16;
typedef unsigned int u32;

DEVI float b2f(u16 u) { u32 x = ((u32)u) << 16; return __builtin_bit_cast(float, x); }
DEVI u16 f2b(float f) {
    u32 u = __builtin_bit_cast(u32, f);
    u32 r = u + 0x7FFFu + ((u >> 16) & 1u);   // RNE
    return (u16)(r >> 16);
}
// fast ELU: exp(v)-1 instead of expm1f; abs err ~1e-7, fine for bf16 pipeline
DEVI float eluf(float v) { return v > 0.f ? v : __expf(v) - 1.f; }

DEVI void gl16(const void* g, void* l) {
    __builtin_amdgcn_global_load_lds(
        (const __attribute__((address_space(1))) u32*)g,
        (__attribute__((address_space(3))) u32*)l, 16, 0, 0);
}

// ---------------- elementwise fp32 -> bf16 ----------------
__global__ void k_convert(const float* __restrict__ in, u16* __restrict__ out, int n) {
    int i = blockIdx.x * blockDim.x + threadIdx.x;
    int stride = gridDim.x * blockDim.x;
    for (int j = i; j * 8 < n; j += stride) {
        int base = j * 8;
        if (base + 8 <= n) {
            float4 a = *(const float4*)(in + base);
            float4 b = *(const float4*)(in + base + 4);
            short8 o;
            o[0] = (short)f2b(a.x); o[1] = (short)f2b(a.y);
            o[2] = (short)f2b(a.z); o[3] = (short)f2b(a.w);
            o[4] = (short)f2b(b.x); o[5] = (short)f2b(b.y);
            o[6] = (short)f2b(b.z); o[7] = (short)f2b(b.w);
            *(short8*)(out + base) = o;
        } else {
            for (int t = base; t < n; ++t) out[t] = f2b(in[t]);
        }
    }
}

// ---------------- build WcT (512 x 128) from w_m1a ----------------
__global__ void k_wct(const float* __restrict__ w, u16* __restrict__ wct) {
    int t = blockIdx.x * 256 + threadIdx.x;
    if (t >= 512 * 128) return;
    int k = t & 127, j = t >> 7;
    float v;
    if (j < 256) v = w[k * 256 + j] + w[(k + 128) * 256 + j];
    else { int jj = j - 256; v = w[(k + 256) * 256 + jj] + w[(k + 384) * 256 + jj]; }
    wct[j * 128 + k] = f2b(v);
}

// ---------------- transpose-convert: W (K x N fp32) -> WT (Nalloc x K bf16) ----------------
__global__ void k_tc(const float* __restrict__ w, u16* __restrict__ wt,
                     int K, int N, int Nalloc) {
    __shared__ float tile[32][33];
    int tx = threadIdx.x, ty = threadIdx.y;
    int k0 = blockIdx.y * 32, n0 = blockIdx.x * 32;
#pragma unroll
    for (int yy = 0; yy < 4; ++yy) {
        int k = k0 + ty + yy * 8, n = n0 + tx;
        tile[ty + yy * 8][tx] = (k < K && n < N) ? w[(size_t)k * N + n] : 0.f;
    }
    __syncthreads();
#pragma unroll
    for (int yy = 0; yy < 4; ++yy) {
        int n = n0 + ty + yy * 8, k = k0 + tx;
        if (n < Nalloc && k < K) wt[(size_t)n * K + k] = f2b(tile[tx][ty + yy * 8]);
    }
}

// ---------------- counting sort of edges by dst ----------------
__global__ void k_hist(const int* __restrict__ ei, int* __restrict__ hist, int E) {
    int i = blockIdx.x * 256 + threadIdx.x;
    if (i < E) atomicAdd(&hist[ei[E + i]], 1);
}

__global__ void k_scan(const int* __restrict__ hist, int* __restrict__ cursor, int NB) {
    __shared__ int part[256];
    int t = threadIdx.x;
    int base = t * 40;
    int s = 0;
    for (int i = 0; i < 40; ++i) { int idx = base + i; if (idx < NB) s += hist[idx]; }
    part[t] = s;
    __syncthreads();
    if (t == 0) { int run = 0; for (int i = 0; i < 256; ++i) { int x = part[i]; part[i] = run; run += x; } }
    __syncthreads();
    int run = part[t];
    for (int i = 0; i < 40; ++i) {
        int idx = base + i;
        if (idx < NB) { int h = hist[idx]; cursor[idx] = run; run += h; }
    }
}

__global__ void k_scatter(const int* __restrict__ ei, int* __restrict__ cursor,
                          int* __restrict__ sdst, int* __restrict__ ssrc, int E) {
    int i = blockIdx.x * 256 + threadIdx.x;
    if (i >= E) return;
    int d = ei[E + i], s = ei[i];
    int pos = atomicAdd(&cursor[d], 1);
    sdst[pos] = d;
    ssrc[pos] = s;
}

// ---------------- generic bf16 GEMM: C = epi(A @ BT^T + bias) ----------------
// EPI: 0 none->bf16, 1 ELU->bf16, 2 ReLU->bf16, 3 sigmoid->fp32
// SWZN>0: 1D grid with bijective XCD swizzle, bx = wg % SWZN, by = wg / SWZN
template <int EPI, int SWZN>
__global__ __launch_bounds__(256, 2)
void k_gemm(const u16* __restrict__ A, const u16* __restrict__ BT,
            const float* __restrict__ bias, void* __restrict__ Cv,
            int M, int N, int K, int lda, int ldbt, int ldc) {
    __shared__ short lsA[128 * 64];
    __shared__ short lsB[128 * 64];
    const int tid = threadIdx.x, wave = tid >> 6, lane = tid & 63;
    int bx, by;
    if (SWZN > 0) {
        int nb = gridDim.x, orig = blockIdx.x;
        int q = nb >> 3, r = nb & 7;
        int x = orig & 7, idx = orig >> 3;
        int wg = (x < r ? x * (q + 1) : r * (q + 1) + (x - r) * q) + idx;
        bx = wg % SWZN; by = wg / SWZN;
    } else { bx = blockIdx.x; by = blockIdx.y; }
    const int m0 = by * 128, n0 = bx * 128;
    const int wm = wave >> 1, wn = wave & 1;
    const int rowA = lane >> 3, colA = (lane & 7) * 8;

    f32x4 acc[4][4] = {};

    const int kch = K >> 6;
    for (int kc = 0; kc < kch; ++kc) {
#pragma unroll
        for (int i = 0; i < 4; ++i) {
            int slot = wave * 4 + i;
            const u16* ga = A + (size_t)(m0 + slot * 8 + rowA) * lda + kc * 64 + colA;
            gl16(ga, &lsA[slot * 512]);
            const u16* gb = BT + (size_t)(n0 + slot * 8 + rowA) * ldbt + kc * 64 + colA;
            gl16(gb, &lsB[slot * 512]);
        }
        __syncthreads();
#pragma unroll
        for (int ks = 0; ks < 2; ++ks) {
            short8 a[4], b[4];
#pragma unroll
            for (int m = 0; m < 4; ++m)
                a[m] = *(const short8*)&lsA[(wm * 64 + m * 16 + (lane & 15)) * 64 + ks * 32 + (lane >> 4) * 8];
#pragma unroll
            for (int n = 0; n < 4; ++n)
                b[n] = *(const short8*)&lsB[(wn * 64 + n * 16 + (lane & 15)) * 64 + ks * 32 + (lane >> 4) * 8];
#pragma unroll
            for (int m = 0; m < 4; ++m)
#pragma unroll
                for (int n = 0; n < 4; ++n)
                    acc[m][n] = __builtin_amdgcn_mfma_f32_16x16x32_bf16(a[m], b[n], acc[m][n], 0, 0, 0);
        }
        __syncthreads();
    }

#pragma unroll
    for (int m = 0; m < 4; ++m) {
#pragma unroll
        for (int n = 0; n < 4; ++n) {
            int colg = n0 + wn * 64 + n * 16 + (lane & 15);
#pragma unroll
            for (int j = 0; j < 4; ++j) {
                int rowg = m0 + wm * 64 + m * 16 + (lane >> 4) * 4 + j;
                if (rowg < M && colg < N) {
                    float v = acc[m][n][j];
                    if (bias) v += bias[colg];
                    if (EPI == 1) v = eluf(v);
                    if (EPI == 2) v = v > 0.f ? v : 0.f;
                    if (EPI == 3) {
                        v = 1.f / (1.f + __expf(-v));
                        ((float*)Cv)[(size_t)rowg * ldc + colg] = v;
                    } else {
                        ((u16*)Cv)[(size_t)rowg * ldc + colg] = f2b(v);
                    }
                }
            }
        }
    }
}

// ---------------- edge kernel v3: sorted edges + segment-reduced atomics ----------------
// 128 sorted edges/block. kc-outer: A-chunk (128x64, 16KB, computed+swizzled) +
// full B (256x64, 32KB, gl16 pre-swizzled src); acc[4 nq][2][4]. Epilogue per nq:
// elu'd tile -> padded fp32 LDS (aliases A/B), per-wave run-length reduce over
// sorted dst, ~1 atomic per (run x 32-row seg x col).
__global__ __launch_bounds__(256, 2)
void k_edge(const u16* __restrict__ P, const int* __restrict__ sdst,
            const int* __restrict__ ssrc, const float* __restrict__ b1,
            const u16* __restrict__ W2T, const float* __restrict__ b2,
            float* __restrict__ agg) {
    __shared__ __align__(16) char smem[49152];   // A:[0,16K) B:[16K,48K) O:[0,34816)
    __shared__ int dstl[128];
    __shared__ int srcl[128];
    short* lsA = (short*)smem;
    short* lsB = (short*)(smem + 16384);
    float* lsO = (float*)smem;                   // 128 x 68 fp32
    const int tid = threadIdx.x, wave = tid >> 6, lane = tid & 63;
    const int eb = blockIdx.x * 128;
    const int g = lane >> 4, l15 = lane & 15;

    if (tid < 128) srcl[tid] = ssrc[eb + tid];
    else dstl[tid - 128] = sdst[eb + (tid - 128)];
    __syncthreads();

    f32x4 acc[4][2][4] = {};

    for (int kc = 0; kc < 4; ++kc) {
        // A-chunk: 128 rows x 64 k = 1024 16B-chunks, 4/thread; swizzle cc ^= r&7
#pragma unroll
        for (int it = 0; it < 4; ++it) {
            int chunk = it * 256 + tid;
            int r = chunk >> 3, cc = chunk & 7;
            int d = dstl[r], s = srcl[r];
            int col = kc * 64 + cc * 8;
            short8 pd = *(const short8*)(P + (size_t)d * 512 + col);
            short8 ps = *(const short8*)(P + (size_t)s * 512 + 256 + col);
            float bv[8];
            *(float4*)&bv[0] = *(const float4*)(b1 + col);
            *(float4*)&bv[4] = *(const float4*)(b1 + col + 4);
            short8 o;
#pragma unroll
            for (int jj = 0; jj < 8; ++jj) {
                float v = b2f((u16)pd[jj]) + b2f((u16)ps[jj]) + bv[jj];
                o[jj] = (short)f2b(eluf(v));
            }
            int ccs = cc ^ (r & 7);
            *(short8*)&lsA[(r * 8 + ccs) * 8] = o;
        }
        // B: 256 rows x 64 k; per wave 8 gl16 calls of 8 rows each
#pragma unroll
        for (int i = 0; i < 8; ++i) {
            int br = (wave * 8 + i) * 8 + (lane >> 3);
            const u16* gb = W2T + (size_t)br * 256 + kc * 64 + (((lane & 7) ^ (br & 7)) * 8);
            gl16(gb, lsB + (wave * 8 + i) * 512);
        }
        __syncthreads();
#pragma unroll
        for (int nq = 0; nq < 4; ++nq) {
#pragma unroll
            for (int ks = 0; ks < 2; ++ks) {
                short8 a[2], b[4];
#pragma unroll
                for (int m = 0; m < 2; ++m) {
                    int ar = wave * 32 + m * 16 + l15;
                    a[m] = *(const short8*)&lsA[(ar * 8 + ((ks * 4 + g) ^ (ar & 7))) * 8];
                }
#pragma unroll
                for (int n = 0; n < 4; ++n) {
                    int br = nq * 64 + n * 16 + l15;
                    b[n] = *(const short8*)&lsB[(br * 8 + ((ks * 4 + g) ^ (br & 7))) * 8];
                }
#pragma unroll
                for (int m = 0; m < 2; ++m)
#pragma unroll
                    for (int n = 0; n < 4; ++n)
                        acc[nq][m][n] = __builtin_amdgcn_mfma_f32_16x16x32_bf16(a[m], b[n], acc[nq][m][n], 0, 0, 0);
            }
        }
        __syncthreads();
    }

    // epilogue: per 64-col quarter, stage elu'd fp32 tile, run-length reduce
#pragma unroll
    for (int nq = 0; nq < 4; ++nq) {
        float b2v[4];
#pragma unroll
        for (int n = 0; n < 4; ++n) b2v[n] = b2[nq * 64 + n * 16 + l15];
#pragma unroll
        for (int m = 0; m < 2; ++m)
#pragma unroll
            for (int n = 0; n < 4; ++n)
#pragma unroll
                for (int j = 0; j < 4; ++j) {
                    int row = wave * 32 + m * 16 + g * 4 + j;
                    lsO[row * 68 + n * 16 + l15] = eluf(acc[nq][m][n][j] + b2v[n]);
                }
        __syncthreads();
        // wave w reduces rows [w*32, w*32+32), lane owns col=lane
        {
            int r0 = wave * 32;
            int dprev = dstl[r0];
            float sum = 0.f;
            for (int i = 0; i < 32; ++i) {
                int row = r0 + i;
                int d = dstl[row];                  // wave-uniform (LDS broadcast)
                float v = lsO[row * 68 + lane];
                if (d != dprev) {
                    atomicAdd(&agg[(size_t)dprev * 256 + nq * 64 + lane], sum);
                    sum = v; dprev = d;
                } else sum += v;
            }
            atomicAdd(&agg[(size_t)dprev * 256 + nq * 64 + lane], sum);
        }
        __syncthreads();
    }
}

extern "C" void kernel_launch(void* const* d_in, const int* in_sizes, int n_in,
                              void* d_out, int out_size, void* d_ws, size_t ws_size,
                              hipStream_t stream) {
    const float* api    = (const float*)d_in[0];
    const int*   ei     = (const int*)d_in[2];
    const float* w_m1a  = (const float*)d_in[7];
    const float* b_m1a  = (const float*)d_in[8];
    const float* w_m1b  = (const float*)d_in[9];
    const float* b_m1b  = (const float*)d_in[10];
    const float* w_m2a  = (const float*)d_in[11];
    const float* b_m2a  = (const float*)d_in[12];
    const float* w_m2b  = (const float*)d_in[13];
    const float* b_m2b  = (const float*)d_in[14];
    const float* w_ma   = (const float*)d_in[15];
    const float* b_ma   = (const float*)d_in[16];
    const float* w_mb   = (const float*)d_in[17];
    const float* b_mb   = (const float*)d_in[18];
    const float* w_inc1 = (const float*)d_in[19];
    const float* b_inc1 = (const float*)d_in[20];
    const float* w_inc2 = (const float*)d_in[21];
    const float* b_inc2 = (const float*)d_in[22];

    const int N = 10000, C = 128, E = 320000, Mp = 10112;   // Mp = 79*128

    char* w = (char*)d_ws;
    size_t off = 0;
    auto alloc = [&](size_t bytes) { void* p = w + off; off += (bytes + 255) & ~(size_t)255; return p; };
    u16* e16   = (u16*)alloc((size_t)Mp * 128 * 2);
    u16* WcT   = (u16*)alloc(512 * 128 * 2);
    u16* P     = (u16*)alloc((size_t)Mp * 512 * 2);
    u16* w1bT  = (u16*)alloc(256 * 256 * 2);
    u16* w2aT  = (u16*)alloc(256 * 256 * 2);
    u16* w2bT  = (u16*)alloc(256 * 256 * 2);
    u16* waT   = (u16*)alloc(256 * 256 * 2);
    u16* wbT   = (u16*)alloc(256 * 256 * 2);
    u16* i1T   = (u16*)alloc(384 * 128 * 2);
    u16* i2T   = (u16*)alloc((size_t)Mp * 384 * 2);
    float* agg = (float*)alloc((size_t)N * 256 * 4);
    u16* agg16 = (u16*)alloc((size_t)Mp * 256 * 2);
    u16* hbA   = (u16*)alloc((size_t)Mp * 256 * 2);
    u16* hbB   = (u16*)alloc((size_t)Mp * 256 * 2);
    u16* H1    = (u16*)alloc((size_t)Mp * 384 * 2);
    int* hist  = (int*)alloc((size_t)N * 4);
    int* cursor= (int*)alloc((size_t)N * 4);
    int* sdst  = (int*)alloc((size_t)E * 4);
    int* ssrc  = (int*)alloc((size_t)E * 4);
    (void)ws_size; (void)in_sizes; (void)n_in; (void)out_size;

    dim3 tb(32, 8);
    // sort edges by dst (counting sort)
    hipMemsetAsync(hist, 0, (size_t)N * 4, stream);
    k_hist<<<1250, 256, 0, stream>>>(ei, hist, E);
    k_scan<<<1, 256, 0, stream>>>(hist, cursor, N);
    k_scatter<<<1250, 256, 0, stream>>>(ei, cursor, sdst, ssrc, E);

    k_convert<<<640, 256, 0, stream>>>(api, e16, N * C);
    k_wct<<<256, 256, 0, stream>>>(w_m1a, WcT);
    k_tc<<<dim3(8, 8),  tb, 0, stream>>>(w_m1b,  w1bT, 256, 256, 256);
    k_tc<<<dim3(8, 8),  tb, 0, stream>>>(w_m2a,  w2aT, 256, 256, 256);
    k_tc<<<dim3(8, 8),  tb, 0, stream>>>(w_m2b,  w2bT, 256, 256, 256);
    k_tc<<<dim3(8, 8),  tb, 0, stream>>>(w_ma,   waT,  256, 256, 256);
    k_tc<<<dim3(8, 8),  tb, 0, stream>>>(w_mb,   wbT,  256, 256, 256);
    k_tc<<<dim3(12, 4), tb, 0, stream>>>(w_inc1, i1T,  128, 384, 384);
    k_tc<<<dim3(316, 12), tb, 0, stream>>>(w_inc2, i2T, 384, 10000, Mp);
    hipMemsetAsync(agg, 0, (size_t)N * 256 * 4, stream);

    // P = e @ Wc  (node projections [pd | ps])
    k_gemm<0, 0><<<dim3(4, 79), 256, 0, stream>>>(e16, WcT, nullptr, P, N, 512, 128, 128, 128, 512);
    // edge layer + segment-sum (sorted)
    k_edge<<<2500, 256, 0, stream>>>(P, sdst, ssrc, b_m1a, w1bT, b_m1b, agg);
    k_convert<<<640, 256, 0, stream>>>(agg, agg16, N * 256);
    // node MLPs
    k_gemm<1, 0><<<dim3(2, 79), 256, 0, stream>>>(agg16, w2aT, b_m2a, hbA, N, 256, 256, 256, 256, 256);
    k_gemm<1, 0><<<dim3(2, 79), 256, 0, stream>>>(hbA,   w2bT, b_m2b, hbB, N, 256, 256, 256, 256, 256);
    k_gemm<1, 0><<<dim3(2, 79), 256, 0, stream>>>(hbB,   waT,  b_ma,  hbA, N, 256, 256, 256, 256, 256);
    k_gemm<1, 0><<<dim3(2, 79), 256, 0, stream>>>(hbA,   wbT,  b_mb,  hbB, N, 256, 256, 256, 256, 256);
    // h[:, -128:] @ w_inc1, ReLU
    k_gemm<2, 0><<<dim3(3, 79), 256, 0, stream>>>(hbB + 128, i1T, b_inc1, H1, N, 384, 128, 256, 128, 384);
    // final: sigmoid(H1 @ w_inc2 + b_inc2) -> d_out fp32, XCD-swizzled
    k_gemm<3, 79><<<dim3(79 * 79), 256, 0, stream>>>(H1, i2T, b_inc2, d_out, N, 10000, 384, 384, 384, 10000);
}

// Round 4
// 530.579 us; speedup vs baseline: 1.6018x; 1.1360x over previous
//
#include <hip/hip_runtime.h>

#define DEVI __device__ __forceinline__

typedef __attribute__((ext_vector_type(8))) short short8;
typedef __attribute__((ext_vector_type(4))) float f32x4;
typedef unsigned short u16;
typedef unsigned int u32;

DEVI float b2f(u16 u) { u32 x = ((u32)u) << 16; return __builtin_bit_cast(float, x); }
DEVI u16 f2b(float f) {
    u32 u = __builtin_bit_cast(u32, f);
    u32 r = u + 0x7FFFu + ((u >> 16) & 1u);   // RNE
    return (u16)(r >> 16);
}
// fast ELU: exp(v)-1 instead of expm1f; abs err ~1e-7, fine for bf16 pipeline
DEVI float eluf(float v) { return v > 0.f ? v : __expf(v) - 1.f; }

DEVI void gl16(const void* g, void* l) {
    __builtin_amdgcn_global_load_lds(
        (const __attribute__((address_space(1))) u32*)g,
        (__attribute__((address_space(3))) u32*)l, 16, 0, 0);
}

// ---------------- elementwise fp32 -> bf16 ----------------
__global__ void k_convert(const float* __restrict__ in, u16* __restrict__ out, int n) {
    int i = blockIdx.x * blockDim.x + threadIdx.x;
    int stride = gridDim.x * blockDim.x;
    for (int j = i; j * 8 < n; j += stride) {
        int base = j * 8;
        if (base + 8 <= n) {
            float4 a = *(const float4*)(in + base);
            float4 b = *(const float4*)(in + base + 4);
            short8 o;
            o[0] = (short)f2b(a.x); o[1] = (short)f2b(a.y);
            o[2] = (short)f2b(a.z); o[3] = (short)f2b(a.w);
            o[4] = (short)f2b(b.x); o[5] = (short)f2b(b.y);
            o[6] = (short)f2b(b.z); o[7] = (short)f2b(b.w);
            *(short8*)(out + base) = o;
        } else {
            for (int t = base; t < n; ++t) out[t] = f2b(in[t]);
        }
    }
}

// ---------------- build WcT (512 x 128) from w_m1a ----------------
__global__ void k_wct(const float* __restrict__ w, u16* __restrict__ wct) {
    int t = blockIdx.x * 256 + threadIdx.x;
    if (t >= 512 * 128) return;
    int k = t & 127, j = t >> 7;
    float v;
    if (j < 256) v = w[k * 256 + j] + w[(k + 128) * 256 + j];
    else { int jj = j - 256; v = w[(k + 256) * 256 + jj] + w[(k + 384) * 256 + jj]; }
    wct[j * 128 + k] = f2b(v);
}

// ---------------- transpose-convert: W (K x N fp32) -> WT (Nalloc x K bf16) ----------------
__global__ void k_tc(const float* __restrict__ w, u16* __restrict__ wt,
                     int K, int N, int Nalloc) {
    __shared__ float tile[32][33];
    int tx = threadIdx.x, ty = threadIdx.y;
    int k0 = blockIdx.y * 32, n0 = blockIdx.x * 32;
#pragma unroll
    for (int yy = 0; yy < 4; ++yy) {
        int k = k0 + ty + yy * 8, n = n0 + tx;
        tile[ty + yy * 8][tx] = (k < K && n < N) ? w[(size_t)k * N + n] : 0.f;
    }
    __syncthreads();
#pragma unroll
    for (int yy = 0; yy < 4; ++yy) {
        int n = n0 + ty + yy * 8, k = k0 + tx;
        if (n < Nalloc && k < K) wt[(size_t)n * K + k] = f2b(tile[tx][ty + yy * 8]);
    }
}

// ---------------- counting sort of edges by dst ----------------
__global__ void k_hist(const int* __restrict__ ei, int* __restrict__ hist, int E) {
    int i = blockIdx.x * 256 + threadIdx.x;
    if (i < E) atomicAdd(&hist[ei[E + i]], 1);
}

__global__ void k_scan(const int* __restrict__ hist, int* __restrict__ cursor, int NB) {
    __shared__ int part[256];
    int t = threadIdx.x;
    int base = t * 40;
    int s = 0;
    for (int i = 0; i < 40; ++i) { int idx = base + i; if (idx < NB) s += hist[idx]; }
    part[t] = s;
    __syncthreads();
    if (t == 0) { int run = 0; for (int i = 0; i < 256; ++i) { int x = part[i]; part[i] = run; run += x; } }
    __syncthreads();
    int run = part[t];
    for (int i = 0; i < 40; ++i) {
        int idx = base + i;
        if (idx < NB) { int h = hist[idx]; cursor[idx] = run; run += h; }
    }
}

__global__ void k_scatter(const int* __restrict__ ei, int* __restrict__ cursor,
                          int* __restrict__ sdst, int* __restrict__ ssrc, int E) {
    int i = blockIdx.x * 256 + threadIdx.x;
    if (i >= E) return;
    int d = ei[E + i], s = ei[i];
    int pos = atomicAdd(&cursor[d], 1);
    sdst[pos] = d;
    ssrc[pos] = s;
}

// ---------------- generic bf16 GEMM (128x128): C = epi(A @ BT^T + bias) ----------------
// EPI: 0 none->bf16, 1 ELU->bf16, 2 ReLU->bf16
template <int EPI>
__global__ __launch_bounds__(256, 2)
void k_gemm(const u16* __restrict__ A, const u16* __restrict__ BT,
            const float* __restrict__ bias, void* __restrict__ Cv,
            int M, int N, int K, int lda, int ldbt, int ldc) {
    __shared__ short lsA[128 * 64];
    __shared__ short lsB[128 * 64];
    const int tid = threadIdx.x, wave = tid >> 6, lane = tid & 63;
    const int bx = blockIdx.x, by = blockIdx.y;
    const int m0 = by * 128, n0 = bx * 128;
    const int wm = wave >> 1, wn = wave & 1;
    const int rowA = lane >> 3, colA = (lane & 7) * 8;

    f32x4 acc[4][4] = {};

    const int kch = K >> 6;
    for (int kc = 0; kc < kch; ++kc) {
#pragma unroll
        for (int i = 0; i < 4; ++i) {
            int slot = wave * 4 + i;
            const u16* ga = A + (size_t)(m0 + slot * 8 + rowA) * lda + kc * 64 + colA;
            gl16(ga, &lsA[slot * 512]);
            const u16* gb = BT + (size_t)(n0 + slot * 8 + rowA) * ldbt + kc * 64 + colA;
            gl16(gb, &lsB[slot * 512]);
        }
        __syncthreads();
#pragma unroll
        for (int ks = 0; ks < 2; ++ks) {
            short8 a[4], b[4];
#pragma unroll
            for (int m = 0; m < 4; ++m)
                a[m] = *(const short8*)&lsA[(wm * 64 + m * 16 + (lane & 15)) * 64 + ks * 32 + (lane >> 4) * 8];
#pragma unroll
            for (int n = 0; n < 4; ++n)
                b[n] = *(const short8*)&lsB[(wn * 64 + n * 16 + (lane & 15)) * 64 + ks * 32 + (lane >> 4) * 8];
#pragma unroll
            for (int m = 0; m < 4; ++m)
#pragma unroll
                for (int n = 0; n < 4; ++n)
                    acc[m][n] = __builtin_amdgcn_mfma_f32_16x16x32_bf16(a[m], b[n], acc[m][n], 0, 0, 0);
        }
        __syncthreads();
    }

#pragma unroll
    for (int m = 0; m < 4; ++m) {
#pragma unroll
        for (int n = 0; n < 4; ++n) {
            int colg = n0 + wn * 64 + n * 16 + (lane & 15);
#pragma unroll
            for (int j = 0; j < 4; ++j) {
                int rowg = m0 + wm * 64 + m * 16 + (lane >> 4) * 4 + j;
                if (rowg < M && colg < N) {
                    float v = acc[m][n][j];
                    if (bias) v += bias[colg];
                    if (EPI == 1) v = eluf(v);
                    if (EPI == 2) v = v > 0.f ? v : 0.f;
                    ((u16*)Cv)[(size_t)rowg * ldc + colg] = f2b(v);
                }
            }
        }
    }
}

// ---------------- final GEMM: 256x128 tile, 8 waves, T2-swizzled LDS, ----------------
// operand-swapped MFMA (lane holds 4 consecutive cols -> dwordx4 stores),
// sigmoid epilogue, fp32 out, bijective chunked XCD swizzle (grid % 8 == 0).
__global__ __launch_bounds__(512, 4)
void k_gemm2(const u16* __restrict__ A, const u16* __restrict__ BT,
             const float* __restrict__ bias, float* __restrict__ C,
             int M, int N, int K, int lda, int ldbt, int ldc, int NBX) {
    __shared__ short lsA[256 * 64];   // 32KB
    __shared__ short lsB[128 * 64];   // 16KB
    const int tid = threadIdx.x, wave = tid >> 6, lane = tid & 63;
    const int g = lane >> 4, l15 = lane & 15;
    const int nb = gridDim.x, orig = blockIdx.x;
    const int cpx = nb >> 3;                      // grid divisible by 8
    const int wg = (orig & 7) * cpx + (orig >> 3);
    const int bx = wg % NBX, by = wg / NBX;
    const int m0 = by * 256, n0 = bx * 128;
    const int wm = wave >> 1, wn = wave & 1;      // 4 x 2 wave grid

    f32x4 acc[4][4] = {};
    const int kch = K >> 6;
    for (int kc = 0; kc < kch; ++kc) {
        // A: 256x64, 32 slots of 8 rows; linear dest + inverse-swizzled source
#pragma unroll
        for (int i = 0; i < 4; ++i) {
            int s = wave * 4 + i;
            int br = s * 8 + (lane >> 3);
            const u16* ga = A + (size_t)(m0 + br) * lda + kc * 64 + (((lane & 7) ^ (br & 7)) * 8);
            gl16(ga, &lsA[s * 512]);
        }
        // B: 128x64, 16 slots
#pragma unroll
        for (int i = 0; i < 2; ++i) {
            int s = wave * 2 + i;
            int br = s * 8 + (lane >> 3);
            const u16* gb = BT + (size_t)(n0 + br) * ldbt + kc * 64 + (((lane & 7) ^ (br & 7)) * 8);
            gl16(gb, &lsB[s * 512]);
        }
        __syncthreads();
#pragma unroll
        for (int ks = 0; ks < 2; ++ks) {
            short8 a[4], b[4];
#pragma unroll
            for (int m = 0; m < 4; ++m) {
                int ar = wm * 64 + m * 16 + l15;
                a[m] = *(const short8*)&lsA[(ar * 8 + ((ks * 4 + g) ^ (ar & 7))) * 8];
            }
#pragma unroll
            for (int n = 0; n < 4; ++n) {
                int br = wn * 64 + n * 16 + l15;
                b[n] = *(const short8*)&lsB[(br * 8 + ((ks * 4 + g) ^ (br & 7))) * 8];
            }
            // swapped operands: D[r][c] with r = B-row space, c = A-row space
            // lane reg j -> C[row = m*16+l15][col = n*16 + 4g + j]
#pragma unroll
            for (int m = 0; m < 4; ++m)
#pragma unroll
                for (int n = 0; n < 4; ++n)
                    acc[m][n] = __builtin_amdgcn_mfma_f32_16x16x32_bf16(b[n], a[m], acc[m][n], 0, 0, 0);
        }
        __syncthreads();
    }

#pragma unroll
    for (int m = 0; m < 4; ++m) {
        int row = m0 + wm * 64 + m * 16 + l15;
        if (row < M) {
#pragma unroll
            for (int n = 0; n < 4; ++n) {
                int col0 = n0 + wn * 64 + n * 16 + g * 4;
                if (col0 < N) {
                    float4 bv = *(const float4*)(bias + col0);
                    float4 o;
                    o.x = 1.f / (1.f + __expf(-(acc[m][n][0] + bv.x)));
                    o.y = 1.f / (1.f + __expf(-(acc[m][n][1] + bv.y)));
                    o.z = 1.f / (1.f + __expf(-(acc[m][n][2] + bv.z)));
                    o.w = 1.f / (1.f + __expf(-(acc[m][n][3] + bv.w)));
                    *(float4*)(C + (size_t)row * ldc + col0) = o;
                }
            }
        }
    }
}

// ---------------- edge kernel v3: sorted edges + segment-reduced atomics ----------------
__global__ __launch_bounds__(256, 2)
void k_edge(const u16* __restrict__ P, const int* __restrict__ sdst,
            const int* __restrict__ ssrc, const float* __restrict__ b1,
            const u16* __restrict__ W2T, const float* __restrict__ b2,
            float* __restrict__ agg) {
    __shared__ __align__(16) char smem[49152];   // A:[0,16K) B:[16K,48K) O:[0,34816)
    __shared__ int dstl[128];
    __shared__ int srcl[128];
    short* lsA = (short*)smem;
    short* lsB = (short*)(smem + 16384);
    float* lsO = (float*)smem;                   // 128 x 68 fp32
    const int tid = threadIdx.x, wave = tid >> 6, lane = tid & 63;
    const int eb = blockIdx.x * 128;
    const int g = lane >> 4, l15 = lane & 15;

    if (tid < 128) srcl[tid] = ssrc[eb + tid];
    else dstl[tid - 128] = sdst[eb + (tid - 128)];
    __syncthreads();

    f32x4 acc[4][2][4] = {};

    for (int kc = 0; kc < 4; ++kc) {
#pragma unroll
        for (int it = 0; it < 4; ++it) {
            int chunk = it * 256 + tid;
            int r = chunk >> 3, cc = chunk & 7;
            int d = dstl[r], s = srcl[r];
            int col = kc * 64 + cc * 8;
            short8 pd = *(const short8*)(P + (size_t)d * 512 + col);
            short8 ps = *(const short8*)(P + (size_t)s * 512 + 256 + col);
            float bv[8];
            *(float4*)&bv[0] = *(const float4*)(b1 + col);
            *(float4*)&bv[4] = *(const float4*)(b1 + col + 4);
            short8 o;
#pragma unroll
            for (int jj = 0; jj < 8; ++jj) {
                float v = b2f((u16)pd[jj]) + b2f((u16)ps[jj]) + bv[jj];
                o[jj] = (short)f2b(eluf(v));
            }
            int ccs = cc ^ (r & 7);
            *(short8*)&lsA[(r * 8 + ccs) * 8] = o;
        }
#pragma unroll
        for (int i = 0; i < 8; ++i) {
            int br = (wave * 8 + i) * 8 + (lane >> 3);
            const u16* gb = W2T + (size_t)br * 256 + kc * 64 + (((lane & 7) ^ (br & 7)) * 8);
            gl16(gb, lsB + (wave * 8 + i) * 512);
        }
        __syncthreads();
#pragma unroll
        for (int nq = 0; nq < 4; ++nq) {
#pragma unroll
            for (int ks = 0; ks < 2; ++ks) {
                short8 a[2], b[4];
#pragma unroll
                for (int m = 0; m < 2; ++m) {
                    int ar = wave * 32 + m * 16 + l15;
                    a[m] = *(const short8*)&lsA[(ar * 8 + ((ks * 4 + g) ^ (ar & 7))) * 8];
                }
#pragma unroll
                for (int n = 0; n < 4; ++n) {
                    int br = nq * 64 + n * 16 + l15;
                    b[n] = *(const short8*)&lsB[(br * 8 + ((ks * 4 + g) ^ (br & 7))) * 8];
                }
#pragma unroll
                for (int m = 0; m < 2; ++m)
#pragma unroll
                    for (int n = 0; n < 4; ++n)
                        acc[nq][m][n] = __builtin_amdgcn_mfma_f32_16x16x32_bf16(a[m], b[n], acc[nq][m][n], 0, 0, 0);
            }
        }
        __syncthreads();
    }

#pragma unroll
    for (int nq = 0; nq < 4; ++nq) {
        float b2v[4];
#pragma unroll
        for (int n = 0; n < 4; ++n) b2v[n] = b2[nq * 64 + n * 16 + l15];
#pragma unroll
        for (int m = 0; m < 2; ++m)
#pragma unroll
            for (int n = 0; n < 4; ++n)
#pragma unroll
                for (int j = 0; j < 4; ++j) {
                    int row = wave * 32 + m * 16 + g * 4 + j;
                    lsO[row * 68 + n * 16 + l15] = eluf(acc[nq][m][n][j] + b2v[n]);
                }
        __syncthreads();
        {
            int r0 = wave * 32;
            int dprev = dstl[r0];
            float sum = 0.f;
            for (int i = 0; i < 32; ++i) {
                int row = r0 + i;
                int d = dstl[row];
                float v = lsO[row * 68 + lane];
                if (d != dprev) {
                    atomicAdd(&agg[(size_t)dprev * 256 + nq * 64 + lane], sum);
                    sum = v; dprev = d;
                } else sum += v;
            }
            atomicAdd(&agg[(size_t)dprev * 256 + nq * 64 + lane], sum);
        }
        __syncthreads();
    }
}

extern "C" void kernel_launch(void* const* d_in, const int* in_sizes, int n_in,
                              void* d_out, int out_size, void* d_ws, size_t ws_size,
                              hipStream_t stream) {
    const float* api    = (const float*)d_in[0];
    const int*   ei     = (const int*)d_in[2];
    const float* w_m1a  = (const float*)d_in[7];
    const float* b_m1a  = (const float*)d_in[8];
    const float* w_m1b  = (const float*)d_in[9];
    const float* b_m1b  = (const float*)d_in[10];
    const float* w_m2a  = (const float*)d_in[11];
    const float* b_m2a  = (const float*)d_in[12];
    const float* w_m2b  = (const float*)d_in[13];
    const float* b_m2b  = (const float*)d_in[14];
    const float* w_ma   = (const float*)d_in[15];
    const float* b_ma   = (const float*)d_in[16];
    const float* w_mb   = (const float*)d_in[17];
    const float* b_mb   = (const float*)d_in[18];
    const float* w_inc1 = (const float*)d_in[19];
    const float* b_inc1 = (const float*)d_in[20];
    const float* w_inc2 = (const float*)d_in[21];
    const float* b_inc2 = (const float*)d_in[22];

    const int N = 10000, C = 128, E = 320000, Mp = 10112;   // Mp = 79*128
    const int Mp2 = 10240;                                   // 40*256 (final-GEMM A rows)

    char* w = (char*)d_ws;
    size_t off = 0;
    auto alloc = [&](size_t bytes) { void* p = w + off; off += (bytes + 255) & ~(size_t)255; return p; };
    u16* e16   = (u16*)alloc((size_t)Mp * 128 * 2);
    u16* WcT   = (u16*)alloc(512 * 128 * 2);
    u16* P     = (u16*)alloc((size_t)Mp * 512 * 2);
    u16* w1bT  = (u16*)alloc(256 * 256 * 2);
    u16* w2aT  = (u16*)alloc(256 * 256 * 2);
    u16* w2bT  = (u16*)alloc(256 * 256 * 2);
    u16* waT   = (u16*)alloc(256 * 256 * 2);
    u16* wbT   = (u16*)alloc(256 * 256 * 2);
    u16* i1T   = (u16*)alloc(384 * 128 * 2);
    u16* i2T   = (u16*)alloc((size_t)Mp * 384 * 2);
    float* agg = (float*)alloc((size_t)N * 256 * 4);
    u16* agg16 = (u16*)alloc((size_t)Mp * 256 * 2);
    u16* hbA   = (u16*)alloc((size_t)Mp * 256 * 2);
    u16* hbB   = (u16*)alloc((size_t)Mp * 256 * 2);
    u16* H1    = (u16*)alloc((size_t)Mp2 * 384 * 2);
    int* hist  = (int*)alloc((size_t)N * 4);
    int* cursor= (int*)alloc((size_t)N * 4);
    int* sdst  = (int*)alloc((size_t)E * 4);
    int* ssrc  = (int*)alloc((size_t)E * 4);
    (void)ws_size; (void)in_sizes; (void)n_in; (void)out_size;

    dim3 tb(32, 8);
    // sort edges by dst (counting sort)
    hipMemsetAsync(hist, 0, (size_t)N * 4, stream);
    k_hist<<<1250, 256, 0, stream>>>(ei, hist, E);
    k_scan<<<1, 256, 0, stream>>>(hist, cursor, N);
    k_scatter<<<1250, 256, 0, stream>>>(ei, cursor, sdst, ssrc, E);

    k_convert<<<640, 256, 0, stream>>>(api, e16, N * C);
    k_wct<<<256, 256, 0, stream>>>(w_m1a, WcT);
    k_tc<<<dim3(8, 8),  tb, 0, stream>>>(w_m1b,  w1bT, 256, 256, 256);
    k_tc<<<dim3(8, 8),  tb, 0, stream>>>(w_m2a,  w2aT, 256, 256, 256);
    k_tc<<<dim3(8, 8),  tb, 0, stream>>>(w_m2b,  w2bT, 256, 256, 256);
    k_tc<<<dim3(8, 8),  tb, 0, stream>>>(w_ma,   waT,  256, 256, 256);
    k_tc<<<dim3(8, 8),  tb, 0, stream>>>(w_mb,   wbT,  256, 256, 256);
    k_tc<<<dim3(12, 4), tb, 0, stream>>>(w_inc1, i1T,  128, 384, 384);
    k_tc<<<dim3(316, 12), tb, 0, stream>>>(w_inc2, i2T, 384, 10000, Mp);
    hipMemsetAsync(agg, 0, (size_t)N * 256 * 4, stream);

    // P = e @ Wc  (node projections [pd | ps])
    k_gemm<0><<<dim3(4, 79), 256, 0, stream>>>(e16, WcT, nullptr, P, N, 512, 128, 128, 128, 512);
    // edge layer + segment-sum (sorted)
    k_edge<<<2500, 256, 0, stream>>>(P, sdst, ssrc, b_m1a, w1bT, b_m1b, agg);
    k_convert<<<640, 256, 0, stream>>>(agg, agg16, N * 256);
    // node MLPs
    k_gemm<1><<<dim3(2, 79), 256, 0, stream>>>(agg16, w2aT, b_m2a, hbA, N, 256, 256, 256, 256, 256);
    k_gemm<1><<<dim3(2, 79), 256, 0, stream>>>(hbA,   w2bT, b_m2b, hbB, N, 256, 256, 256, 256, 256);
    k_gemm<1><<<dim3(2, 79), 256, 0, stream>>>(hbB,   waT,  b_ma,  hbA, N, 256, 256, 256, 256, 256);
    k_gemm<1><<<dim3(2, 79), 256, 0, stream>>>(hbA,   wbT,  b_mb,  hbB, N, 256, 256, 256, 256, 256);
    // h[:, -128:] @ w_inc1, ReLU
    k_gemm<2><<<dim3(3, 79), 256, 0, stream>>>(hbB + 128, i1T, b_inc1, H1, N, 384, 128, 256, 128, 384);
    // final: sigmoid(H1 @ w_inc2 + b_inc2) -> d_out fp32 (256x128 tiles, 40x79 grid)
    k_gemm2<<<40 * 79, 512, 0, stream>>>(H1, i2T, b_inc2, (float*)d_out,
                                         N, 10000, 384, 384, 384, 10000, 79);
}